// Round 9
// baseline (3286.507 us; speedup 1.0000x reference)
//
#include <hip/hip_runtime.h>
#include <math.h>

#define NN 5000
#define NE 80000
#define EPSB 1e-3f
#define GZ 100   // gram k-slices (50 rows each)

// bf16 helpers (RNE pack / unpack)
__device__ __forceinline__ unsigned int f2bf(float f) {
    unsigned int u = __float_as_uint(f);
    return (u + 0x7FFFu + ((u >> 16) & 1u)) >> 16;
}
__device__ __forceinline__ float bf2f(unsigned short h) {
    return __uint_as_float(((unsigned int)h) << 16);
}

// ------------------------------------------- prep: pad x + degree count ----

__global__ void k_prep(const float* __restrict__ x, float* __restrict__ x_p,
                       const int* __restrict__ ei, int* __restrict__ counts) {
    int t = blockIdx.x * 256 + threadIdx.x;
    if (t < NN * 36) {
        int n = t / 36, i = t - n * 36;
        x_p[t] = (i < 35) ? x[n * 35 + i] : 0.f;
    }
    if (t < NE) atomicAdd(&counts[ei[NE + t]], 1);
}

__global__ void k_scan(const int* __restrict__ counts, int* __restrict__ offs) {
    __shared__ int ps[256];
    int t = threadIdx.x;
    int base = t * 20;
    int loc[20];
    int s = 0;
#pragma unroll
    for (int j = 0; j < 20; ++j) {
        int idx = base + j;
        int v = (idx < NN) ? counts[idx] : 0;
        loc[j] = s; s += v;
    }
    ps[t] = s;
    __syncthreads();
    for (int off = 1; off < 256; off <<= 1) {
        int v = (t >= off) ? ps[t - off] : 0;
        __syncthreads();
        ps[t] += v;
        __syncthreads();
    }
    int pre = (t > 0) ? ps[t - 1] : 0;
#pragma unroll
    for (int j = 0; j < 20; ++j) {
        int idx = base + j;
        if (idx < NN) offs[idx] = pre + loc[j];
    }
    if (t == 255) offs[NN] = ps[255];
}

// slot -> edge list (CSR order)
__global__ void k_fill(const int* __restrict__ ei, const int* __restrict__ offs,
                       int* __restrict__ cursor, int* __restrict__ elist) {
    int e = blockIdx.x * blockDim.x + threadIdx.x;
    if (e >= NE) return;
    int dst = ei[NE + e];
    int p = atomicAdd(&cursor[dst], 1);
    elist[offs[dst] + p] = e;
}

// ------------------- layer 1 phase 1: per-slot messages, column-major out --
// msg1T layout [35][NE]: lane-consecutive slots -> coalesced 2B stores.

__global__ __launch_bounds__(256) void k_edge1(
    const int* __restrict__ ei, const float* __restrict__ ea,
    const int* __restrict__ elist,
    const float* __restrict__ x_p,
    const float* __restrict__ W1, const float* __restrict__ b1,
    unsigned short* __restrict__ msg1T)
{
    __shared__ float wls[35][36];
    __shared__ float bls[35][36];
    for (int idx = threadIdx.x; idx < 35 * 36; idx += 256) {
        int i = idx / 36, o = idx - i * 36;
        wls[i][o] = (o < 35) ? W1[i * 35 + o] : 0.f;
        bls[i][o] = (o < 35) ? b1[i * 35 + o] : 0.f;
    }
    __syncthreads();
    int s = blockIdx.x * 256 + threadIdx.x;
    if (s >= NE) return;
    int e = elist[s];
    int src = ei[e];
    float a = ea[e];
    const float4* xp4 = (const float4*)(x_p + src * 36);
    float acc[35];
#pragma unroll
    for (int o = 0; o < 35; ++o) acc[o] = 0.f;
#pragma unroll
    for (int q = 0; q < 9; ++q) {
        float4 xv = xp4[q];
        float xs4[4] = {xv.x, xv.y, xv.z, xv.w};
#pragma unroll
        for (int r = 0; r < 4; ++r) {
            int i = q * 4 + r;
            if (i >= 35) continue;
            float xi = xs4[r];
#pragma unroll
            for (int o = 0; o < 35; ++o)
                acc[o] = fmaf(xi, fmaxf(0.f, fmaf(a, wls[i][o], bls[i][o])), acc[o]);
        }
    }
#pragma unroll
    for (int o = 0; o < 35; ++o)
        msg1T[(size_t)o * NE + s] = (unsigned short)f2bf(acc[o]);
}

// ----------------------------------- layer 1 phase 2: stream + finalize ----
// grid (79, 9), block (64,4): wave = one o (uniform), lanes = consecutive n.

__global__ __launch_bounds__(256) void k_sum1(
    const int* __restrict__ offs,
    const unsigned short* __restrict__ msg1T,
    const float* __restrict__ x_p,
    const float* __restrict__ root1, const float* __restrict__ bias1,
    const float* __restrict__ g, const float* __restrict__ be,
    const float* __restrict__ rm, const float* __restrict__ rv,
    float* __restrict__ x1p)
{
    __shared__ float xs[64][37];   // stride 37: lane-stride 5 mod 32, conflict-free
    int nb = blockIdx.x * 64;
    int tid = threadIdx.y * 64 + threadIdx.x;
    for (int idx = tid; idx < 64 * 36; idx += 256) {
        int rr = idx / 36, cc = idx - rr * 36;
        int n = nb + rr;
        xs[rr][cc] = (n < NN) ? x_p[n * 36 + cc] : 0.f;
    }
    __syncthreads();
    int n = nb + threadIdx.x;
    int o = blockIdx.y * 4 + threadIdx.y;
    if (n >= NN) return;
    if (o >= 35) { x1p[n * 36 + 35] = 0.f; return; }
    int off = offs[n], deg = offs[n + 1] - off;
    const unsigned short* base = msg1T + (size_t)o * NE + off;
    float s = 0.f;
    int j = 0;
    int head = (4 - (off & 3)) & 3; if (head > deg) head = deg;
    for (; j < head; ++j) s += bf2f(base[j]);
    for (; j + 4 <= deg; j += 4) {
        uint2 u = *(const uint2*)(base + j);
        s += bf2f((unsigned short)(u.x & 0xffff)) + bf2f((unsigned short)(u.x >> 16))
           + bf2f((unsigned short)(u.y & 0xffff)) + bf2f((unsigned short)(u.y >> 16));
    }
    for (; j < deg; ++j) s += bf2f(base[j]);
    float mean = s / fmaxf((float)deg, 1.0f);
    float r = 0.f;
#pragma unroll 7
    for (int i = 0; i < 35; ++i) r = fmaf(xs[threadIdx.x][i], root1[i * 35 + o], r);
    float h = mean + r + bias1[o];
    float z = (h - rm[o]) * (g[o] * rsqrtf(rv[o] + EPSB)) + be[o];
    x1p[n * 36 + o] = 1.f / (1.f + expf(-z));
}

// ------------------- layer 3 phase 1: 2 slots/thread, column-major out -----
// grid (157, 5): o-chunk = 32 outputs, msg3T layout [160][NE].

__global__ __launch_bounds__(256) void k_edge3(
    const int* __restrict__ ei, const float* __restrict__ ea,
    const int* __restrict__ elist,
    const float* __restrict__ x1p,
    const float* __restrict__ W3, const float* __restrict__ b3,
    unsigned short* __restrict__ msg3T)
{
    __shared__ float wls[35][32];
    __shared__ float bls[35][32];
    int ob = blockIdx.y * 32;
    for (int idx = threadIdx.x; idx < 35 * 32; idx += 256) {
        int i = idx >> 5, o = idx & 31;
        wls[i][o] = W3[i * 160 + ob + o];
        bls[i][o] = b3[i * 160 + ob + o];
    }
    __syncthreads();
    int s0 = blockIdx.x * 512 + threadIdx.x;
    int s1 = s0 + 256;
    bool v0 = s0 < NE, v1 = s1 < NE;
    int e0 = v0 ? elist[s0] : 0;
    int e1 = v1 ? elist[s1] : 0;
    int srcA = v0 ? ei[e0] : 0;
    int srcB = v1 ? ei[e1] : 0;
    float aA = v0 ? ea[e0] : 0.f;
    float aB = v1 ? ea[e1] : 0.f;
    const float4* xA = (const float4*)(x1p + srcA * 36);
    const float4* xB = (const float4*)(x1p + srcB * 36);
    float accA[32], accB[32];
#pragma unroll
    for (int o = 0; o < 32; ++o) { accA[o] = 0.f; accB[o] = 0.f; }
#pragma unroll
    for (int q = 0; q < 9; ++q) {
        float4 va = xA[q], vb = xB[q];
        float fa[4] = {va.x, va.y, va.z, va.w};
        float fb[4] = {vb.x, vb.y, vb.z, vb.w};
#pragma unroll
        for (int r = 0; r < 4; ++r) {
            int i = q * 4 + r;
            if (i >= 35) continue;
            float xa = fa[r], xb = fb[r];
#pragma unroll
            for (int o = 0; o < 32; ++o) {
                float w = wls[i][o], bb = bls[i][o];
                accA[o] = fmaf(xa, fmaxf(0.f, fmaf(aA, w, bb)), accA[o]);
                accB[o] = fmaf(xb, fmaxf(0.f, fmaf(aB, w, bb)), accB[o]);
            }
        }
    }
#pragma unroll
    for (int o = 0; o < 32; ++o) {
        size_t row = (size_t)(ob + o) * NE;
        if (v0) msg3T[row + s0] = (unsigned short)f2bf(accA[o]);
        if (v1) msg3T[row + s1] = (unsigned short)f2bf(accB[o]);
    }
}

// ----------------------------------- layer 3 phase 2: stream + finalize ----
// grid (79, 40), block (64,4): wave = one o, lanes = consecutive n.

__global__ __launch_bounds__(256) void k_sum3(
    const int* __restrict__ offs,
    const unsigned short* __restrict__ msg3T,
    const float* __restrict__ x1p,
    const float* __restrict__ root3, const float* __restrict__ bias3,
    const float* __restrict__ g, const float* __restrict__ be,
    const float* __restrict__ rm, const float* __restrict__ rv,
    float* __restrict__ x3)
{
    __shared__ float xs[64][37];
    int nb = blockIdx.x * 64;
    int tid = threadIdx.y * 64 + threadIdx.x;
    for (int idx = tid; idx < 64 * 36; idx += 256) {
        int rr = idx / 36, cc = idx - rr * 36;
        int n = nb + rr;
        xs[rr][cc] = (n < NN) ? x1p[n * 36 + cc] : 0.f;
    }
    __syncthreads();
    int n = nb + threadIdx.x;
    int o = blockIdx.y * 4 + threadIdx.y;
    if (n >= NN) return;
    int off = offs[n], deg = offs[n + 1] - off;
    const unsigned short* base = msg3T + (size_t)o * NE + off;
    float s = 0.f;
    int j = 0;
    int head = (4 - (off & 3)) & 3; if (head > deg) head = deg;
    for (; j < head; ++j) s += bf2f(base[j]);
    for (; j + 4 <= deg; j += 4) {
        uint2 u = *(const uint2*)(base + j);
        s += bf2f((unsigned short)(u.x & 0xffff)) + bf2f((unsigned short)(u.x >> 16))
           + bf2f((unsigned short)(u.y & 0xffff)) + bf2f((unsigned short)(u.y >> 16));
    }
    for (; j < deg; ++j) s += bf2f(base[j]);
    float mean = s / fmaxf((float)deg, 1.0f);
    float r = 0.f;
#pragma unroll 7
    for (int i = 0; i < 35; ++i) r = fmaf(xs[threadIdx.x][i], root3[i * 160 + o], r);
    float h = mean + r + bias3[o];
    float z = (h - rm[o]) * (g[o] * rsqrtf(rv[o] + EPSB)) + be[o];
    x3[n * 160 + o] = 1.f / (1.f + expf(-z));
}

// ----------------------------------------------------------- gram ----------
// grid (3,3,GZ) k-chunk 50; unrolled for load ILP

__global__ void k_gram(const float* __restrict__ x3, float* __restrict__ part) {
    int tx = threadIdx.x, ty = threadIdx.y;
    int i = blockIdx.x * 64 + tx * 4;
    int j = blockIdx.y * 64 + ty * 4;
    if (i >= 160 || j >= 160) return;
    int k0 = blockIdx.z * 50;
    float acc[4][4];
#pragma unroll
    for (int r = 0; r < 4; ++r)
#pragma unroll
        for (int c = 0; c < 4; ++c) acc[r][c] = 0.f;
#pragma unroll 5
    for (int k = k0; k < k0 + 50; ++k) {
        float4 av = *(const float4*)&x3[k * 160 + i];
        float4 bv = *(const float4*)&x3[k * 160 + j];
        float ar[4] = {av.x, av.y, av.z, av.w};
        float br[4] = {bv.x, bv.y, bv.z, bv.w};
#pragma unroll
        for (int r = 0; r < 4; ++r)
#pragma unroll
            for (int c = 0; c < 4; ++c) acc[r][c] = fmaf(ar[r], br[c], acc[r][c]);
    }
    float* pp = part + (size_t)blockIdx.z * 25600;
#pragma unroll
    for (int r = 0; r < 4; ++r)
#pragma unroll
        for (int c = 0; c < 4; ++c) pp[(i + r) * 160 + (j + c)] = acc[r][c];
}

__global__ void k_reduce(const float* __restrict__ part, float* __restrict__ out) {
    int t = blockIdx.x * 256 + threadIdx.x;
    if (t >= 25600) return;
    float s = 0.f;
#pragma unroll 10
    for (int z = 0; z < GZ; ++z) s += part[(size_t)z * 25600 + t];
    out[t] = s;
}

// ----------------------------------------------------------------- launch --

extern "C" void kernel_launch(void* const* d_in, const int* in_sizes, int n_in,
                              void* d_out, int out_size, void* d_ws, size_t ws_size,
                              hipStream_t stream) {
    const float* x     = (const float*)d_in[0];
    const int*   ei    = (const int*)d_in[1];
    const float* ea    = (const float*)d_in[2];
    const float* W1    = (const float*)d_in[3];
    const float* b1    = (const float*)d_in[4];
    const float* root1 = (const float*)d_in[5];
    const float* bias1 = (const float*)d_in[6];
    const float* g1    = (const float*)d_in[7];
    const float* be1   = (const float*)d_in[8];
    const float* rm1   = (const float*)d_in[9];
    const float* rv1   = (const float*)d_in[10];
    const float* W3    = (const float*)d_in[11];
    const float* b3    = (const float*)d_in[12];
    const float* root3 = (const float*)d_in[13];
    const float* bias3 = (const float*)d_in[14];
    const float* g3    = (const float*)d_in[15];
    const float* be3   = (const float*)d_in[16];
    const float* rm3   = (const float*)d_in[17];
    const float* rv3   = (const float*)d_in[18];
    float* out = (float*)d_out;

    // ---- workspace layout (byte offsets, all 16B-aligned) ----
    char* wsb = (char*)d_ws;
    int*   counts = (int*)(wsb + 0);                    //  20480 B
    int*   cursor = (int*)(wsb + 20480);                //  20480 B
    int*   offs   = (int*)(wsb + 40960);                //  20480 B
    int*   elist  = (int*)(wsb + 61440);                // 320512 B -> end 381952
    float* x_p    = (float*)(wsb + 381952);             // 720000 B -> end 1101952
    float* x1p    = (float*)(wsb + 1101952);            // 720000 B -> end 1821952
    float* x3     = (float*)(wsb + 1821952);            // 3.2 MB  -> end 5021952
    unsigned short* msg1T = (unsigned short*)(wsb + 5021952);  // 36 rows -> end 10781952
    unsigned short* msg3T = (unsigned short*)(wsb + 10781952); // 160 rows -> end 36381952
    float* part   = (float*)(wsb + 5021952);            // 10.24 MB, aliases msg1T+msg3T (dead)

    hipMemsetAsync(d_ws, 0, (size_t)2 * 5120 * sizeof(int), stream);  // counts+cursor

    int eb = (NE + 255) / 256;
    k_prep <<<(NN * 36 + 255) / 256, 256, 0, stream>>>(x, x_p, ei, counts);
    k_scan <<<1, 256, 0, stream>>>(counts, offs);
    k_fill <<<eb, 256, 0, stream>>>(ei, offs, cursor, elist);
    k_edge1<<<eb, 256, 0, stream>>>(ei, ea, elist, x_p, W1, b1, msg1T);
    k_sum1 <<<dim3(79, 9), dim3(64, 4), 0, stream>>>(offs, msg1T, x_p,
                                                     root1, bias1, g1, be1, rm1, rv1, x1p);
    k_edge3<<<dim3((NE + 511) / 512, 5), 256, 0, stream>>>(ei, ea, elist, x1p, W3, b3, msg3T);
    k_sum3 <<<dim3(79, 40), dim3(64, 4), 0, stream>>>(offs, msg3T, x1p,
                                                      root3, bias3, g3, be3, rm3, rv3, x3);
    k_gram <<<dim3(3, 3, GZ), dim3(16, 16), 0, stream>>>(x3, part);
    k_reduce<<<(25600 + 255) / 256, 256, 0, stream>>>(part, out);
}

// Round 13
// 279.661 us; speedup vs baseline: 11.7518x; 11.7518x over previous
//
#include <hip/hip_runtime.h>
#include <math.h>

#define NN 5000
#define NE 80000
#define EPSB 1e-3f
#define GZ 100   // gram k-slices (50 rows each)

// bf16 helpers (RNE pack / unpack)
__device__ __forceinline__ unsigned int f2bf(float f) {
    unsigned int u = __float_as_uint(f);
    return (u + 0x7FFFu + ((u >> 16) & 1u)) >> 16;
}
__device__ __forceinline__ float bf2f(unsigned short h) {
    return __uint_as_float(((unsigned int)h) << 16);
}

// ------------------------------------------- prep: pad x + degree count ----

__global__ void k_prep(const float* __restrict__ x, float* __restrict__ x_p,
                       const int* __restrict__ ei, int* __restrict__ counts) {
    int t = blockIdx.x * 256 + threadIdx.x;
    if (t < NN * 36) {
        int n = t / 36, i = t - n * 36;
        x_p[t] = (i < 35) ? x[n * 35 + i] : 0.f;
    }
    if (t < NE) atomicAdd(&counts[ei[NE + t]], 1);
}

__global__ void k_scan(const int* __restrict__ counts, int* __restrict__ offs) {
    __shared__ int ps[256];
    int t = threadIdx.x;
    int base = t * 20;
    int loc[20];
    int s = 0;
#pragma unroll
    for (int j = 0; j < 20; ++j) {
        int idx = base + j;
        int v = (idx < NN) ? counts[idx] : 0;
        loc[j] = s; s += v;
    }
    ps[t] = s;
    __syncthreads();
    for (int off = 1; off < 256; off <<= 1) {
        int v = (t >= off) ? ps[t - off] : 0;
        __syncthreads();
        ps[t] += v;
        __syncthreads();
    }
    int pre = (t > 0) ? ps[t - 1] : 0;
#pragma unroll
    for (int j = 0; j < 20; ++j) {
        int idx = base + j;
        if (idx < NN) offs[idx] = pre + loc[j];
    }
    if (t == 255) offs[NN] = ps[255];
}

// per-edge CSR slot (messages get written directly in CSR order)
__global__ void k_fill(const int* __restrict__ ei, const int* __restrict__ offs,
                       int* __restrict__ cursor, int* __restrict__ eslot) {
    int e = blockIdx.x * blockDim.x + threadIdx.x;
    if (e >= NE) return;
    int dst = ei[NE + e];
    int p = atomicAdd(&cursor[dst], 1);
    eslot[e] = offs[dst] + p;
}

// ------------------------------------- layer 1 phase 1: per-edge messages --

__global__ __launch_bounds__(256) void k_edge1(
    const int* __restrict__ ei, const float* __restrict__ ea,
    const int* __restrict__ eslot,
    const float* __restrict__ x_p,
    const float* __restrict__ W1, const float* __restrict__ b1,
    unsigned short* __restrict__ msg1)
{
    __shared__ float wls[36][36];
    __shared__ float bls[36][36];
    for (int idx = threadIdx.x; idx < 1296; idx += 256) {
        int i = idx / 36, o = idx - i * 36;
        bool in = (i < 35) && (o < 35);
        wls[i][o] = in ? W1[i * 35 + o] : 0.f;
        bls[i][o] = in ? b1[i * 35 + o] : 0.f;
    }
    __syncthreads();
    int e = blockIdx.x * 256 + threadIdx.x;
    if (e >= NE) return;
    int src = ei[e];
    float a = ea[e];
    const float4* xp4 = (const float4*)(x_p + src * 36);
    float acc[36];
#pragma unroll
    for (int o = 0; o < 36; ++o) acc[o] = 0.f;
    float4 xv = xp4[0];
#pragma unroll 1
    for (int q = 0; q < 9; ++q) {
        float4 xn = (q < 8) ? xp4[q + 1] : xv;
        float xs4[4] = {xv.x, xv.y, xv.z, xv.w};
#pragma unroll
        for (int r = 0; r < 4; ++r) {
            int i = q * 4 + r;
            float xvr = xs4[r];
            const float4* wr = (const float4*)(&wls[i][0]);
            const float4* br = (const float4*)(&bls[i][0]);
#pragma unroll
            for (int oq = 0; oq < 9; ++oq) {
                float4 wv = wr[oq], bv = br[oq];
                int o0 = oq * 4;
                acc[o0 + 0] = fmaf(xvr, fmaxf(0.f, fmaf(a, wv.x, bv.x)), acc[o0 + 0]);
                acc[o0 + 1] = fmaf(xvr, fmaxf(0.f, fmaf(a, wv.y, bv.y)), acc[o0 + 1]);
                acc[o0 + 2] = fmaf(xvr, fmaxf(0.f, fmaf(a, wv.z, bv.z)), acc[o0 + 2]);
                acc[o0 + 3] = fmaf(xvr, fmaxf(0.f, fmaf(a, wv.w, bv.w)), acc[o0 + 3]);
            }
        }
        xv = xn;
    }
    unsigned int pk[18];
#pragma unroll
    for (int k = 0; k < 18; ++k)
        pk[k] = f2bf(acc[2 * k]) | (f2bf(acc[2 * k + 1]) << 16);
    uint2* dst = (uint2*)(msg1 + (size_t)eslot[e] * 36);
#pragma unroll
    for (int j = 0; j < 9; ++j) dst[j] = make_uint2(pk[2 * j], pk[2 * j + 1]);
}

// ----------------------------------- layer 1 phase 2: gather + finalize ----

__global__ __launch_bounds__(256) void k_sum1(
    const int* __restrict__ offs,
    const unsigned short* __restrict__ msg1,
    const float* __restrict__ x_p,
    const float* __restrict__ root1, const float* __restrict__ bias1,
    const float* __restrict__ g, const float* __restrict__ be,
    const float* __restrict__ rm, const float* __restrict__ rv,
    float* __restrict__ x1p)
{
    int t = blockIdx.x * 256 + threadIdx.x;
    if (t >= NN * 36) return;
    int n = t / 36, o = t - n * 36;
    if (o == 35) { x1p[t] = 0.f; return; }
    int off = offs[n];
    int deg = offs[n + 1] - off;
    const unsigned short* base = msg1 + (size_t)off * 36 + o;
    float s = 0.f;
    for (int j = 0; j < deg; ++j) s += bf2f(base[(size_t)j * 36]);
    float mean = s / fmaxf((float)deg, 1.0f);
    float r = 0.f;
#pragma unroll 7
    for (int i = 0; i < 35; ++i) r = fmaf(x_p[n * 36 + i], root1[i * 35 + o], r);
    float h = mean + r + bias1[o];
    float z = (h - rm[o]) * (g[o] * rsqrtf(rv[o] + EPSB)) + be[o];
    x1p[t] = 1.f / (1.f + expf(-z));
}

// ------------------------------------- layer 3 phase 1: per-edge messages --
// thread = TWO edges x 32-output chunk (gridDim.y = 5). msg layout [5][slot][32].
// W/b staged in LDS (padded i=35 row zero); q-loop unroll 1 caps VGPR.

__global__ __launch_bounds__(256) void k_edge3(
    const int* __restrict__ ei, const float* __restrict__ ea,
    const int* __restrict__ eslot,
    const float* __restrict__ x1p,
    const float* __restrict__ W3, const float* __restrict__ b3,
    unsigned short* __restrict__ msg3)
{
    __shared__ float wls[36][32];
    __shared__ float bls[36][32];
    int ob = blockIdx.y * 32;
    for (int idx = threadIdx.x; idx < 1152; idx += 256) {
        int i = idx >> 5, o = idx & 31;
        bool in = (i < 35);
        wls[i][o] = in ? W3[i * 160 + ob + o] : 0.f;
        bls[i][o] = in ? b3[i * 160 + ob + o] : 0.f;
    }
    __syncthreads();
    int e0 = blockIdx.x * 512 + threadIdx.x;
    int e1 = e0 + 256;
    bool v0 = e0 < NE, v1 = e1 < NE;
    int eA = v0 ? e0 : 0, eB = v1 ? e1 : 0;
    int srcA = ei[eA], srcB = ei[eB];
    float aA = ea[eA], aB = ea[eB];
    const float4* xA4 = (const float4*)(x1p + srcA * 36);
    const float4* xB4 = (const float4*)(x1p + srcB * 36);
    float accA[32], accB[32];
#pragma unroll
    for (int o = 0; o < 32; ++o) { accA[o] = 0.f; accB[o] = 0.f; }
#pragma unroll 1
    for (int q = 0; q < 9; ++q) {
        float4 va = xA4[q], vb = xB4[q];
        float fa[4] = {va.x, va.y, va.z, va.w};
        float fb[4] = {vb.x, vb.y, vb.z, vb.w};
#pragma unroll
        for (int r = 0; r < 4; ++r) {
            int i = q * 4 + r;          // i=35 row is zero-padded: contributes 0
            float xa = fa[r], xb = fb[r];
            const float4* wr = (const float4*)(&wls[i][0]);
            const float4* br = (const float4*)(&bls[i][0]);
#pragma unroll
            for (int oq = 0; oq < 8; ++oq) {
                float4 wv = wr[oq], bv = br[oq];
                int o0 = oq * 4;
                accA[o0 + 0] = fmaf(xa, fmaxf(0.f, fmaf(aA, wv.x, bv.x)), accA[o0 + 0]);
                accA[o0 + 1] = fmaf(xa, fmaxf(0.f, fmaf(aA, wv.y, bv.y)), accA[o0 + 1]);
                accA[o0 + 2] = fmaf(xa, fmaxf(0.f, fmaf(aA, wv.z, bv.z)), accA[o0 + 2]);
                accA[o0 + 3] = fmaf(xa, fmaxf(0.f, fmaf(aA, wv.w, bv.w)), accA[o0 + 3]);
                accB[o0 + 0] = fmaf(xb, fmaxf(0.f, fmaf(aB, wv.x, bv.x)), accB[o0 + 0]);
                accB[o0 + 1] = fmaf(xb, fmaxf(0.f, fmaf(aB, wv.y, bv.y)), accB[o0 + 1]);
                accB[o0 + 2] = fmaf(xb, fmaxf(0.f, fmaf(aB, wv.z, bv.z)), accB[o0 + 2]);
                accB[o0 + 3] = fmaf(xb, fmaxf(0.f, fmaf(aB, wv.w, bv.w)), accB[o0 + 3]);
            }
        }
    }
    unsigned int pk[16];
    if (v0) {
#pragma unroll
        for (int k = 0; k < 16; ++k)
            pk[k] = f2bf(accA[2 * k]) | (f2bf(accA[2 * k + 1]) << 16);
        uint4* dst = (uint4*)(msg3 + ((size_t)blockIdx.y * NE + eslot[e0]) * 32);
#pragma unroll
        for (int j = 0; j < 4; ++j)
            dst[j] = make_uint4(pk[4 * j], pk[4 * j + 1], pk[4 * j + 2], pk[4 * j + 3]);
    }
    if (v1) {
#pragma unroll
        for (int k = 0; k < 16; ++k)
            pk[k] = f2bf(accB[2 * k]) | (f2bf(accB[2 * k + 1]) << 16);
        uint4* dst = (uint4*)(msg3 + ((size_t)blockIdx.y * NE + eslot[e1]) * 32);
#pragma unroll
        for (int j = 0; j < 4; ++j)
            dst[j] = make_uint4(pk[4 * j], pk[4 * j + 1], pk[4 * j + 2], pk[4 * j + 3]);
    }
}

// ----------------------------------- layer 3 phase 2: gather + finalize ----
// block 320 = 4 nodes x 80 lanes; each lane 2 adjacent outputs (one uint load/row)

__global__ __launch_bounds__(320) void k_sum3(
    const int* __restrict__ offs,
    const unsigned short* __restrict__ msg3,
    const float* __restrict__ x1p,
    const float* __restrict__ root3, const float* __restrict__ bias3,
    const float* __restrict__ g, const float* __restrict__ be,
    const float* __restrict__ rm, const float* __restrict__ rv,
    float* __restrict__ x3)
{
    __shared__ float xn[4][36];
    int tid = threadIdx.x;
    int g_ = tid / 80;
    int o2 = tid - g_ * 80;
    int o  = o2 * 2;
    int n  = blockIdx.x * 4 + g_;
    if (tid < 144) xn[tid / 36][tid % 36] = x1p[(blockIdx.x * 4 + tid / 36) * 36 + tid % 36];
    __syncthreads();
    int off = offs[n];
    int deg = offs[n + 1] - off;
    int chunk = o >> 5, oo = o & 31;
    const unsigned short* base = msg3 + ((size_t)chunk * NE + off) * 32 + oo;
    float s0 = 0.f, s1 = 0.f;
    for (int j = 0; j < deg; ++j) {
        unsigned int u = *(const unsigned int*)(base + (size_t)j * 32);
        s0 += bf2f((unsigned short)(u & 0xffff));
        s1 += bf2f((unsigned short)(u >> 16));
    }
    float inv = 1.f / fmaxf((float)deg, 1.0f);
    float m0 = s0 * inv, m1 = s1 * inv;
    float r0 = 0.f, r1 = 0.f;
#pragma unroll 7
    for (int i = 0; i < 35; ++i) {
        float xvi = xn[g_][i];
        r0 = fmaf(xvi, root3[i * 160 + o], r0);
        r1 = fmaf(xvi, root3[i * 160 + o + 1], r1);
    }
    float h0 = m0 + r0 + bias3[o];
    float h1 = m1 + r1 + bias3[o + 1];
    float z0 = (h0 - rm[o]) * (g[o] * rsqrtf(rv[o] + EPSB)) + be[o];
    float z1 = (h1 - rm[o + 1]) * (g[o + 1] * rsqrtf(rv[o + 1] + EPSB)) + be[o + 1];
    float2 res = make_float2(1.f / (1.f + expf(-z0)), 1.f / (1.f + expf(-z1)));
    *(float2*)(x3 + n * 160 + o) = res;
}

// ----------------------------------------------------------- gram ----------
// grid (3,3,GZ) k-chunk 50; unrolled for load ILP

__global__ void k_gram(const float* __restrict__ x3, float* __restrict__ part) {
    int tx = threadIdx.x, ty = threadIdx.y;
    int i = blockIdx.x * 64 + tx * 4;
    int j = blockIdx.y * 64 + ty * 4;
    if (i >= 160 || j >= 160) return;
    int k0 = blockIdx.z * 50;
    float acc[4][4];
#pragma unroll
    for (int r = 0; r < 4; ++r)
#pragma unroll
        for (int c = 0; c < 4; ++c) acc[r][c] = 0.f;
#pragma unroll 5
    for (int k = k0; k < k0 + 50; ++k) {
        float4 av = *(const float4*)&x3[k * 160 + i];
        float4 bv = *(const float4*)&x3[k * 160 + j];
        float ar[4] = {av.x, av.y, av.z, av.w};
        float br[4] = {bv.x, bv.y, bv.z, bv.w};
#pragma unroll
        for (int r = 0; r < 4; ++r)
#pragma unroll
            for (int c = 0; c < 4; ++c) acc[r][c] = fmaf(ar[r], br[c], acc[r][c]);
    }
    float* pp = part + (size_t)blockIdx.z * 25600;
#pragma unroll
    for (int r = 0; r < 4; ++r)
#pragma unroll
        for (int c = 0; c < 4; ++c) pp[(i + r) * 160 + (j + c)] = acc[r][c];
}

__global__ void k_reduce(const float* __restrict__ part, float* __restrict__ out) {
    int t = blockIdx.x * 256 + threadIdx.x;
    if (t >= 25600) return;
    float s = 0.f;
#pragma unroll 10
    for (int z = 0; z < GZ; ++z) s += part[(size_t)z * 25600 + t];
    out[t] = s;
}

// ----------------------------------------------------------------- launch --

extern "C" void kernel_launch(void* const* d_in, const int* in_sizes, int n_in,
                              void* d_out, int out_size, void* d_ws, size_t ws_size,
                              hipStream_t stream) {
    const float* x     = (const float*)d_in[0];
    const int*   ei    = (const int*)d_in[1];
    const float* ea    = (const float*)d_in[2];
    const float* W1    = (const float*)d_in[3];
    const float* b1    = (const float*)d_in[4];
    const float* root1 = (const float*)d_in[5];
    const float* bias1 = (const float*)d_in[6];
    const float* g1    = (const float*)d_in[7];
    const float* be1   = (const float*)d_in[8];
    const float* rm1   = (const float*)d_in[9];
    const float* rv1   = (const float*)d_in[10];
    const float* W3    = (const float*)d_in[11];
    const float* b3    = (const float*)d_in[12];
    const float* root3 = (const float*)d_in[13];
    const float* bias3 = (const float*)d_in[14];
    const float* g3    = (const float*)d_in[15];
    const float* be3   = (const float*)d_in[16];
    const float* rm3   = (const float*)d_in[17];
    const float* rv3   = (const float*)d_in[18];
    float* out = (float*)d_out;

    // ---- workspace layout (byte offsets, all 16B-aligned) ----
    char* wsb = (char*)d_ws;
    int*   counts = (int*)(wsb + 0);                    //  20480 B
    int*   cursor = (int*)(wsb + 20480);                //  20480 B
    int*   offs   = (int*)(wsb + 40960);                //  20480 B
    int*   eslot  = (int*)(wsb + 61440);                // 320512 B -> end 381952
    float* x_p    = (float*)(wsb + 381952);             // 720000 B -> end 1101952
    float* x1p    = (float*)(wsb + 1101952);            // 720000 B -> end 1821952
    float* x3     = (float*)(wsb + 1821952);            // 3.2 MB  -> end 5021952
    unsigned short* msg1 = (unsigned short*)(wsb + 5021952);  // 5.76 MB -> end 10781952
    unsigned short* msg3 = (unsigned short*)(wsb + 10781952); // 25.6 MB -> end 36381952
    float* part   = (float*)(wsb + 5021952);            // 10.24 MB, aliases msg1 (dead)

    hipMemsetAsync(d_ws, 0, (size_t)2 * 5120 * sizeof(int), stream);  // counts+cursor

    int eb = (NE + 255) / 256;
    k_prep <<<(NN * 36 + 255) / 256, 256, 0, stream>>>(x, x_p, ei, counts);
    k_scan <<<1, 256, 0, stream>>>(counts, offs);
    k_fill <<<eb, 256, 0, stream>>>(ei, offs, cursor, eslot);
    k_edge1<<<eb, 256, 0, stream>>>(ei, ea, eslot, x_p, W1, b1, msg1);
    k_sum1 <<<(NN * 36 + 255) / 256, 256, 0, stream>>>(offs, msg1, x_p,
                                                       root1, bias1, g1, be1, rm1, rv1, x1p);
    k_edge3<<<dim3((NE + 511) / 512, 5), 256, 0, stream>>>(ei, ea, eslot, x1p, W3, b3, msg3);
    k_sum3 <<<1250, 320, 0, stream>>>(offs, msg3, x1p,
                                      root3, bias3, g3, be3, rm3, rv3, x3);
    k_gram <<<dim3(3, 3, GZ), dim3(16, 16), 0, stream>>>(x3, part);
    k_reduce<<<(25600 + 255) / 256, 256, 0, stream>>>(part, out);
}

// Round 15
// 238.286 us; speedup vs baseline: 13.7923x; 1.1736x over previous
//
#include <hip/hip_runtime.h>
#include <math.h>

#define NN 5000
#define NE 80000
#define EPSB 1e-3f
#define GZ 100   // gram k-slices (50 rows each)

// bf16 helpers (RNE pack / unpack)
__device__ __forceinline__ unsigned int f2bf(float f) {
    unsigned int u = __float_as_uint(f);
    return (u + 0x7FFFu + ((u >> 16) & 1u)) >> 16;
}
__device__ __forceinline__ float bf2f(unsigned short h) {
    return __uint_as_float(((unsigned int)h) << 16);
}

// ------------------------------------------- prep: pad x + degree count ----

__global__ void k_prep(const float* __restrict__ x, float* __restrict__ x_p,
                       const int* __restrict__ ei, int* __restrict__ counts) {
    int t = blockIdx.x * 256 + threadIdx.x;
    if (t < NN * 36) {
        int n = t / 36, i = t - n * 36;
        x_p[t] = (i < 35) ? x[n * 35 + i] : 0.f;
    }
    if (t < NE) atomicAdd(&counts[ei[NE + t]], 1);
}

__global__ void k_scan(const int* __restrict__ counts, int* __restrict__ offs) {
    __shared__ int ps[256];
    int t = threadIdx.x;
    int base = t * 20;
    int loc[20];
    int s = 0;
#pragma unroll
    for (int j = 0; j < 20; ++j) {
        int idx = base + j;
        int v = (idx < NN) ? counts[idx] : 0;
        loc[j] = s; s += v;
    }
    ps[t] = s;
    __syncthreads();
    for (int off = 1; off < 256; off <<= 1) {
        int v = (t >= off) ? ps[t - off] : 0;
        __syncthreads();
        ps[t] += v;
        __syncthreads();
    }
    int pre = (t > 0) ? ps[t - 1] : 0;
#pragma unroll
    for (int j = 0; j < 20; ++j) {
        int idx = base + j;
        if (idx < NN) offs[idx] = pre + loc[j];
    }
    if (t == 255) offs[NN] = ps[255];
}

// --------------- layer 1 phase 1: per-edge messages (+ inline slot alloc) --

__global__ __launch_bounds__(256) void k_edge1(
    const int* __restrict__ ei, const float* __restrict__ ea,
    const int* __restrict__ offs, int* __restrict__ cursor,
    int* __restrict__ eslot,
    const float* __restrict__ x_p,
    const float* __restrict__ W1, const float* __restrict__ b1,
    unsigned short* __restrict__ msg1)
{
    __shared__ float wls[36][36];
    __shared__ float bls[36][36];
    for (int idx = threadIdx.x; idx < 1296; idx += 256) {
        int i = idx / 36, o = idx - i * 36;
        bool in = (i < 35) && (o < 35);
        wls[i][o] = in ? W1[i * 35 + o] : 0.f;
        bls[i][o] = in ? b1[i * 35 + o] : 0.f;
    }
    __syncthreads();
    int e = blockIdx.x * 256 + threadIdx.x;
    if (e >= NE) return;
    int dstn = ei[NE + e];
    int p = atomicAdd(&cursor[dstn], 1);
    int slot = offs[dstn] + p;
    eslot[e] = slot;

    int src = ei[e];
    float a = ea[e];
    const float4* xp4 = (const float4*)(x_p + src * 36);
    float acc[36];
#pragma unroll
    for (int o = 0; o < 36; ++o) acc[o] = 0.f;
    float4 xv = xp4[0];
#pragma unroll 1
    for (int q = 0; q < 9; ++q) {
        float4 xn = (q < 8) ? xp4[q + 1] : xv;
        float xs4[4] = {xv.x, xv.y, xv.z, xv.w};
#pragma unroll
        for (int r = 0; r < 4; ++r) {
            int i = q * 4 + r;
            float xvr = xs4[r];
            const float4* wr = (const float4*)(&wls[i][0]);
            const float4* br = (const float4*)(&bls[i][0]);
#pragma unroll
            for (int oq = 0; oq < 9; ++oq) {
                float4 wv = wr[oq], bv = br[oq];
                int o0 = oq * 4;
                acc[o0 + 0] = fmaf(xvr, fmaxf(0.f, fmaf(a, wv.x, bv.x)), acc[o0 + 0]);
                acc[o0 + 1] = fmaf(xvr, fmaxf(0.f, fmaf(a, wv.y, bv.y)), acc[o0 + 1]);
                acc[o0 + 2] = fmaf(xvr, fmaxf(0.f, fmaf(a, wv.z, bv.z)), acc[o0 + 2]);
                acc[o0 + 3] = fmaf(xvr, fmaxf(0.f, fmaf(a, wv.w, bv.w)), acc[o0 + 3]);
            }
        }
        xv = xn;
    }
    unsigned int pk[18];
#pragma unroll
    for (int k = 0; k < 18; ++k)
        pk[k] = f2bf(acc[2 * k]) | (f2bf(acc[2 * k + 1]) << 16);
    uint2* dst = (uint2*)(msg1 + (size_t)slot * 36);
#pragma unroll
    for (int j = 0; j < 9; ++j) dst[j] = make_uint2(pk[2 * j], pk[2 * j + 1]);
}

// ----------------------------------- layer 1 phase 2: gather + finalize ----

__global__ __launch_bounds__(256) void k_sum1(
    const int* __restrict__ offs,
    const unsigned short* __restrict__ msg1,
    const float* __restrict__ x_p,
    const float* __restrict__ root1, const float* __restrict__ bias1,
    const float* __restrict__ g, const float* __restrict__ be,
    const float* __restrict__ rm, const float* __restrict__ rv,
    float* __restrict__ x1p)
{
    int t = blockIdx.x * 256 + threadIdx.x;
    if (t >= NN * 36) return;
    int n = t / 36, o = t - n * 36;
    if (o == 35) { x1p[t] = 0.f; return; }
    int off = offs[n];
    int deg = offs[n + 1] - off;
    const unsigned short* base = msg1 + (size_t)off * 36 + o;
    float s = 0.f;
    for (int j = 0; j < deg; ++j) s += bf2f(base[(size_t)j * 36]);
    float mean = s / fmaxf((float)deg, 1.0f);
    float r = 0.f;
#pragma unroll 7
    for (int i = 0; i < 35; ++i) r = fmaf(x_p[n * 36 + i], root1[i * 35 + o], r);
    float h = mean + r + bias1[o];
    float z = (h - rm[o]) * (g[o] * rsqrtf(rv[o] + EPSB)) + be[o];
    x1p[t] = 1.f / (1.f + expf(-z));
}

// ------------------------------------- layer 3 phase 1: per-edge messages --
// round-6 exact: thread = one edge x 32-output chunk (gridDim.y = 5).

__global__ __launch_bounds__(256) void k_edge3(
    const int* __restrict__ ei, const float* __restrict__ ea,
    const int* __restrict__ eslot,
    const float* __restrict__ x1p,
    const float* __restrict__ W3, const float* __restrict__ b3,
    unsigned short* __restrict__ msg3)
{
    __shared__ float wls[36][32];
    __shared__ float bls[36][32];
    int ob = blockIdx.y * 32;
    for (int idx = threadIdx.x; idx < 1152; idx += 256) {
        int i = idx >> 5, o = idx & 31;
        bool in = (i < 35);
        wls[i][o] = in ? W3[i * 160 + ob + o] : 0.f;
        bls[i][o] = in ? b3[i * 160 + ob + o] : 0.f;
    }
    __syncthreads();
    int e = blockIdx.x * 256 + threadIdx.x;
    if (e >= NE) return;
    int src = ei[e];
    float a = ea[e];
    const float4* xp4 = (const float4*)(x1p + src * 36);
    float acc[32];
#pragma unroll
    for (int o = 0; o < 32; ++o) acc[o] = 0.f;
    float4 xv = xp4[0];
#pragma unroll 1
    for (int q = 0; q < 9; ++q) {
        float4 xn = (q < 8) ? xp4[q + 1] : xv;
        float xs4[4] = {xv.x, xv.y, xv.z, xv.w};
#pragma unroll
        for (int r = 0; r < 4; ++r) {
            int i = q * 4 + r;
            float xvr = xs4[r];
            const float4* wr = (const float4*)(&wls[i][0]);
            const float4* br = (const float4*)(&bls[i][0]);
#pragma unroll
            for (int oq = 0; oq < 8; ++oq) {
                float4 wv = wr[oq], bv = br[oq];
                int o0 = oq * 4;
                acc[o0 + 0] = fmaf(xvr, fmaxf(0.f, fmaf(a, wv.x, bv.x)), acc[o0 + 0]);
                acc[o0 + 1] = fmaf(xvr, fmaxf(0.f, fmaf(a, wv.y, bv.y)), acc[o0 + 1]);
                acc[o0 + 2] = fmaf(xvr, fmaxf(0.f, fmaf(a, wv.z, bv.z)), acc[o0 + 2]);
                acc[o0 + 3] = fmaf(xvr, fmaxf(0.f, fmaf(a, wv.w, bv.w)), acc[o0 + 3]);
            }
        }
        xv = xn;
    }
    unsigned int pk[16];
#pragma unroll
    for (int k = 0; k < 16; ++k)
        pk[k] = f2bf(acc[2 * k]) | (f2bf(acc[2 * k + 1]) << 16);
    uint4* dst = (uint4*)(msg3 + ((size_t)blockIdx.y * NE + eslot[e]) * 32);
#pragma unroll
    for (int j = 0; j < 4; ++j)
        dst[j] = make_uint4(pk[4 * j], pk[4 * j + 1], pk[4 * j + 2], pk[4 * j + 3]);
}

// ----------------------------------- layer 3 phase 2: gather + finalize ----

__global__ __launch_bounds__(320) void k_sum3(
    const int* __restrict__ offs,
    const unsigned short* __restrict__ msg3,
    const float* __restrict__ x1p,
    const float* __restrict__ root3, const float* __restrict__ bias3,
    const float* __restrict__ g, const float* __restrict__ be,
    const float* __restrict__ rm, const float* __restrict__ rv,
    float* __restrict__ x3)
{
    __shared__ float xn[4][36];
    int tid = threadIdx.x;
    int g_ = tid / 80;
    int o2 = tid - g_ * 80;
    int o  = o2 * 2;
    int n  = blockIdx.x * 4 + g_;
    if (tid < 144) xn[tid / 36][tid % 36] = x1p[(blockIdx.x * 4 + tid / 36) * 36 + tid % 36];
    __syncthreads();
    int off = offs[n];
    int deg = offs[n + 1] - off;
    int chunk = o >> 5, oo = o & 31;
    const unsigned short* base = msg3 + ((size_t)chunk * NE + off) * 32 + oo;
    float s0 = 0.f, s1 = 0.f;
    for (int j = 0; j < deg; ++j) {
        unsigned int u = *(const unsigned int*)(base + (size_t)j * 32);
        s0 += bf2f((unsigned short)(u & 0xffff));
        s1 += bf2f((unsigned short)(u >> 16));
    }
    float inv = 1.f / fmaxf((float)deg, 1.0f);
    float m0 = s0 * inv, m1 = s1 * inv;
    float r0 = 0.f, r1 = 0.f;
#pragma unroll 7
    for (int i = 0; i < 35; ++i) {
        float xvi = xn[g_][i];
        r0 = fmaf(xvi, root3[i * 160 + o], r0);
        r1 = fmaf(xvi, root3[i * 160 + o + 1], r1);
    }
    float h0 = m0 + r0 + bias3[o];
    float h1 = m1 + r1 + bias3[o + 1];
    float z0 = (h0 - rm[o]) * (g[o] * rsqrtf(rv[o] + EPSB)) + be[o];
    float z1 = (h1 - rm[o + 1]) * (g[o + 1] * rsqrtf(rv[o + 1] + EPSB)) + be[o + 1];
    float2 res = make_float2(1.f / (1.f + expf(-z0)), 1.f / (1.f + expf(-z1)));
    *(float2*)(x3 + n * 160 + o) = res;
}

// ----------------------------------------------------------- gram ----------

__global__ void k_gram(const float* __restrict__ x3, float* __restrict__ part) {
    int tx = threadIdx.x, ty = threadIdx.y;
    int i = blockIdx.x * 64 + tx * 4;
    int j = blockIdx.y * 64 + ty * 4;
    if (i >= 160 || j >= 160) return;
    int k0 = blockIdx.z * 50;
    float acc[4][4];
#pragma unroll
    for (int r = 0; r < 4; ++r)
#pragma unroll
        for (int c = 0; c < 4; ++c) acc[r][c] = 0.f;
#pragma unroll 5
    for (int k = k0; k < k0 + 50; ++k) {
        float4 av = *(const float4*)&x3[k * 160 + i];
        float4 bv = *(const float4*)&x3[k * 160 + j];
        float ar[4] = {av.x, av.y, av.z, av.w};
        float br[4] = {bv.x, bv.y, bv.z, bv.w};
#pragma unroll
        for (int r = 0; r < 4; ++r)
#pragma unroll
            for (int c = 0; c < 4; ++c) acc[r][c] = fmaf(ar[r], br[c], acc[r][c]);
    }
    float* pp = part + (size_t)blockIdx.z * 25600;
#pragma unroll
    for (int r = 0; r < 4; ++r)
#pragma unroll
        for (int c = 0; c < 4; ++c) pp[(i + r) * 160 + (j + c)] = acc[r][c];
}

__global__ void k_reduce(const float* __restrict__ part, float* __restrict__ out) {
    int t = blockIdx.x * 256 + threadIdx.x;
    if (t >= 25600) return;
    float s = 0.f;
#pragma unroll 10
    for (int z = 0; z < GZ; ++z) s += part[(size_t)z * 25600 + t];
    out[t] = s;
}

// ----------------------------------------------------------------- launch --

extern "C" void kernel_launch(void* const* d_in, const int* in_sizes, int n_in,
                              void* d_out, int out_size, void* d_ws, size_t ws_size,
                              hipStream_t stream) {
    const float* x     = (const float*)d_in[0];
    const int*   ei    = (const int*)d_in[1];
    const float* ea    = (const float*)d_in[2];
    const float* W1    = (const float*)d_in[3];
    const float* b1    = (const float*)d_in[4];
    const float* root1 = (const float*)d_in[5];
    const float* bias1 = (const float*)d_in[6];
    const float* g1    = (const float*)d_in[7];
    const float* be1   = (const float*)d_in[8];
    const float* rm1   = (const float*)d_in[9];
    const float* rv1   = (const float*)d_in[10];
    const float* W3    = (const float*)d_in[11];
    const float* b3    = (const float*)d_in[12];
    const float* root3 = (const float*)d_in[13];
    const float* bias3 = (const float*)d_in[14];
    const float* g3    = (const float*)d_in[15];
    const float* be3   = (const float*)d_in[16];
    const float* rm3   = (const float*)d_in[17];
    const float* rv3   = (const float*)d_in[18];
    float* out = (float*)d_out;

    // ---- workspace layout (byte offsets, all 16B-aligned) ----
    char* wsb = (char*)d_ws;
    int*   counts = (int*)(wsb + 0);                    //  20480 B
    int*   cursor = (int*)(wsb + 20480);                //  20480 B
    int*   offs   = (int*)(wsb + 40960);                //  20480 B
    int*   eslot  = (int*)(wsb + 61440);                // 320512 B -> end 381952
    float* x_p    = (float*)(wsb + 381952);             // 720000 B -> end 1101952
    float* x1p    = (float*)(wsb + 1101952);            // 720000 B -> end 1821952
    float* x3     = (float*)(wsb + 1821952);            // 3.2 MB  -> end 5021952
    unsigned short* msg1 = (unsigned short*)(wsb + 5021952);  // 5.76 MB -> end 10781952
    unsigned short* msg3 = (unsigned short*)(wsb + 10781952); // 25.6 MB -> end 36381952
    float* part   = (float*)(wsb + 5021952);            // 10.24 MB, aliases msg1 (dead)

    hipMemsetAsync(d_ws, 0, (size_t)2 * 5120 * sizeof(int), stream);  // counts+cursor

    int eb = (NE + 255) / 256;
    k_prep <<<(NN * 36 + 255) / 256, 256, 0, stream>>>(x, x_p, ei, counts);
    k_scan <<<1, 256, 0, stream>>>(counts, offs);
    k_edge1<<<eb, 256, 0, stream>>>(ei, ea, offs, cursor, eslot, x_p, W1, b1, msg1);
    k_sum1 <<<(NN * 36 + 255) / 256, 256, 0, stream>>>(offs, msg1, x_p,
                                                       root1, bias1, g1, be1, rm1, rv1, x1p);
    k_edge3<<<dim3(eb, 5), 256, 0, stream>>>(ei, ea, eslot, x1p, W3, b3, msg3);
    k_sum3 <<<1250, 320, 0, stream>>>(offs, msg3, x1p,
                                      root3, bias3, g3, be3, rm3, rv3, x3);
    k_gram <<<dim3(3, 3, GZ), dim3(16, 16), 0, stream>>>(x3, part);
    k_reduce<<<(25600 + 255) / 256, 256, 0, stream>>>(part, out);
}

// Round 16
// 237.357 us; speedup vs baseline: 13.8463x; 1.0039x over previous
//
#include <hip/hip_runtime.h>
#include <math.h>

#define NN 5000
#define NE 80000
#define EPSB 1e-3f
#define GZ 100   // gram k-slices (50 rows each)

// bf16 helpers (RNE pack / unpack)
__device__ __forceinline__ unsigned int f2bf(float f) {
    unsigned int u = __float_as_uint(f);
    return (u + 0x7FFFu + ((u >> 16) & 1u)) >> 16;
}
__device__ __forceinline__ float bf2f(unsigned short h) {
    return __uint_as_float(((unsigned int)h) << 16);
}

// ------------------------------------------- prep: pad x + degree count ----

__global__ void k_prep(const float* __restrict__ x, float* __restrict__ x_p,
                       const int* __restrict__ ei, int* __restrict__ counts) {
    int t = blockIdx.x * 256 + threadIdx.x;
    if (t < NN * 36) {
        int n = t / 36, i = t - n * 36;
        x_p[t] = (i < 35) ? x[n * 35 + i] : 0.f;
    }
    if (t < NE) atomicAdd(&counts[ei[NE + t]], 1);
}

__global__ void k_scan(const int* __restrict__ counts, int* __restrict__ offs) {
    __shared__ int ps[256];
    int t = threadIdx.x;
    int base = t * 20;
    int loc[20];
    int s = 0;
#pragma unroll
    for (int j = 0; j < 20; ++j) {
        int idx = base + j;
        int v = (idx < NN) ? counts[idx] : 0;
        loc[j] = s; s += v;
    }
    ps[t] = s;
    __syncthreads();
    for (int off = 1; off < 256; off <<= 1) {
        int v = (t >= off) ? ps[t - off] : 0;
        __syncthreads();
        ps[t] += v;
        __syncthreads();
    }
    int pre = (t > 0) ? ps[t - 1] : 0;
#pragma unroll
    for (int j = 0; j < 20; ++j) {
        int idx = base + j;
        if (idx < NN) offs[idx] = pre + loc[j];
    }
    if (t == 255) offs[NN] = ps[255];
}

// --------------- layer 1 phase 1: per-edge messages (+ inline slot alloc) --

__global__ __launch_bounds__(256) void k_edge1(
    const int* __restrict__ ei, const float* __restrict__ ea,
    const int* __restrict__ offs, int* __restrict__ cursor,
    int* __restrict__ eslot,
    const float* __restrict__ x_p,
    const float* __restrict__ W1, const float* __restrict__ b1,
    unsigned short* __restrict__ msg1)
{
    __shared__ float wls[36][36];
    __shared__ float bls[36][36];
    for (int idx = threadIdx.x; idx < 1296; idx += 256) {
        int i = idx / 36, o = idx - i * 36;
        bool in = (i < 35) && (o < 35);
        wls[i][o] = in ? W1[i * 35 + o] : 0.f;
        bls[i][o] = in ? b1[i * 35 + o] : 0.f;
    }
    __syncthreads();
    int e = blockIdx.x * 256 + threadIdx.x;
    if (e >= NE) return;
    int dstn = ei[NE + e];
    int p = atomicAdd(&cursor[dstn], 1);
    int slot = offs[dstn] + p;
    eslot[e] = slot;

    int src = ei[e];
    float a = ea[e];
    const float4* xp4 = (const float4*)(x_p + src * 36);
    float acc[36];
#pragma unroll
    for (int o = 0; o < 36; ++o) acc[o] = 0.f;
    float4 xv = xp4[0];
#pragma unroll 1
    for (int q = 0; q < 9; ++q) {
        float4 xn = (q < 8) ? xp4[q + 1] : xv;
        float xs4[4] = {xv.x, xv.y, xv.z, xv.w};
#pragma unroll
        for (int r = 0; r < 4; ++r) {
            int i = q * 4 + r;
            float xvr = xs4[r];
            const float4* wr = (const float4*)(&wls[i][0]);
            const float4* br = (const float4*)(&bls[i][0]);
#pragma unroll
            for (int oq = 0; oq < 9; ++oq) {
                float4 wv = wr[oq], bv = br[oq];
                int o0 = oq * 4;
                acc[o0 + 0] = fmaf(xvr, fmaxf(0.f, fmaf(a, wv.x, bv.x)), acc[o0 + 0]);
                acc[o0 + 1] = fmaf(xvr, fmaxf(0.f, fmaf(a, wv.y, bv.y)), acc[o0 + 1]);
                acc[o0 + 2] = fmaf(xvr, fmaxf(0.f, fmaf(a, wv.z, bv.z)), acc[o0 + 2]);
                acc[o0 + 3] = fmaf(xvr, fmaxf(0.f, fmaf(a, wv.w, bv.w)), acc[o0 + 3]);
            }
        }
        xv = xn;
    }
    unsigned int pk[18];
#pragma unroll
    for (int k = 0; k < 18; ++k)
        pk[k] = f2bf(acc[2 * k]) | (f2bf(acc[2 * k + 1]) << 16);
    uint2* dst = (uint2*)(msg1 + (size_t)slot * 36);
#pragma unroll
    for (int j = 0; j < 9; ++j) dst[j] = make_uint2(pk[2 * j], pk[2 * j + 1]);
}

// ----------------------------------- layer 1 phase 2: gather + finalize ----

__global__ __launch_bounds__(256) void k_sum1(
    const int* __restrict__ offs,
    const unsigned short* __restrict__ msg1,
    const float* __restrict__ x_p,
    const float* __restrict__ root1, const float* __restrict__ bias1,
    const float* __restrict__ g, const float* __restrict__ be,
    const float* __restrict__ rm, const float* __restrict__ rv,
    float* __restrict__ x1p)
{
    int t = blockIdx.x * 256 + threadIdx.x;
    if (t >= NN * 36) return;
    int n = t / 36, o = t - n * 36;
    if (o == 35) { x1p[t] = 0.f; return; }
    int off = offs[n];
    int deg = offs[n + 1] - off;
    const unsigned short* base = msg1 + (size_t)off * 36 + o;
    float s = 0.f;
    for (int j = 0; j < deg; ++j) s += bf2f(base[(size_t)j * 36]);
    float mean = s / fmaxf((float)deg, 1.0f);
    float r = 0.f;
#pragma unroll 7
    for (int i = 0; i < 35; ++i) r = fmaf(x_p[n * 36 + i], root1[i * 35 + o], r);
    float h = mean + r + bias1[o];
    float z = (h - rm[o]) * (g[o] * rsqrtf(rv[o] + EPSB)) + be[o];
    x1p[t] = 1.f / (1.f + expf(-z));
}

// ------------------------------------- layer 3 phase 1: per-edge messages --
// thread = one edge x 16-output chunk (gridDim.y = 10). msg layout [10][slot][16].
// Same total work as 5x32, but 2x blocks/waves -> latency hiding; acc 16 floats.

__global__ __launch_bounds__(256) void k_edge3(
    const int* __restrict__ ei, const float* __restrict__ ea,
    const int* __restrict__ eslot,
    const float* __restrict__ x1p,
    const float* __restrict__ W3, const float* __restrict__ b3,
    unsigned short* __restrict__ msg3)
{
    __shared__ float wls[36][16];
    __shared__ float bls[36][16];
    int ob = blockIdx.y * 16;
    for (int idx = threadIdx.x; idx < 576; idx += 256) {
        int i = idx >> 4, o = idx & 15;
        bool in = (i < 35);
        wls[i][o] = in ? W3[i * 160 + ob + o] : 0.f;
        bls[i][o] = in ? b3[i * 160 + ob + o] : 0.f;
    }
    __syncthreads();
    int e = blockIdx.x * 256 + threadIdx.x;
    if (e >= NE) return;
    int src = ei[e];
    float a = ea[e];
    const float4* xp4 = (const float4*)(x1p + src * 36);
    float acc[16];
#pragma unroll
    for (int o = 0; o < 16; ++o) acc[o] = 0.f;
    float4 xv = xp4[0];
#pragma unroll 1
    for (int q = 0; q < 9; ++q) {
        float4 xn = (q < 8) ? xp4[q + 1] : xv;
        float xs4[4] = {xv.x, xv.y, xv.z, xv.w};
#pragma unroll
        for (int r = 0; r < 4; ++r) {
            int i = q * 4 + r;           // i=35 row zero-padded
            float xvr = xs4[r];
            const float4* wr = (const float4*)(&wls[i][0]);
            const float4* br = (const float4*)(&bls[i][0]);
#pragma unroll
            for (int oq = 0; oq < 4; ++oq) {
                float4 wv = wr[oq], bv = br[oq];
                int o0 = oq * 4;
                acc[o0 + 0] = fmaf(xvr, fmaxf(0.f, fmaf(a, wv.x, bv.x)), acc[o0 + 0]);
                acc[o0 + 1] = fmaf(xvr, fmaxf(0.f, fmaf(a, wv.y, bv.y)), acc[o0 + 1]);
                acc[o0 + 2] = fmaf(xvr, fmaxf(0.f, fmaf(a, wv.z, bv.z)), acc[o0 + 2]);
                acc[o0 + 3] = fmaf(xvr, fmaxf(0.f, fmaf(a, wv.w, bv.w)), acc[o0 + 3]);
            }
        }
        xv = xn;
    }
    unsigned int pk[8];
#pragma unroll
    for (int k = 0; k < 8; ++k)
        pk[k] = f2bf(acc[2 * k]) | (f2bf(acc[2 * k + 1]) << 16);
    uint4* dst = (uint4*)(msg3 + ((size_t)blockIdx.y * NE + eslot[e]) * 16);
    dst[0] = make_uint4(pk[0], pk[1], pk[2], pk[3]);
    dst[1] = make_uint4(pk[4], pk[5], pk[6], pk[7]);
}

// ----------------------------------- layer 3 phase 2: gather + finalize ----
// block 320 = 4 nodes x 80 lanes; lane = 2 adjacent outputs (one uint load/row).
// msg layout now [10][slot][16]: chunk = o>>4 (o even -> o,o+1 same chunk).

__global__ __launch_bounds__(320) void k_sum3(
    const int* __restrict__ offs,
    const unsigned short* __restrict__ msg3,
    const float* __restrict__ x1p,
    const float* __restrict__ root3, const float* __restrict__ bias3,
    const float* __restrict__ g, const float* __restrict__ be,
    const float* __restrict__ rm, const float* __restrict__ rv,
    float* __restrict__ x3)
{
    __shared__ float xn[4][36];
    int tid = threadIdx.x;
    int g_ = tid / 80;
    int o2 = tid - g_ * 80;
    int o  = o2 * 2;
    int n  = blockIdx.x * 4 + g_;
    if (tid < 144) xn[tid / 36][tid % 36] = x1p[(blockIdx.x * 4 + tid / 36) * 36 + tid % 36];
    __syncthreads();
    int off = offs[n];
    int deg = offs[n + 1] - off;
    int chunk = o >> 4, oo = o & 15;
    const unsigned short* base = msg3 + ((size_t)chunk * NE + off) * 16 + oo;
    float s0 = 0.f, s1 = 0.f;
    for (int j = 0; j < deg; ++j) {
        unsigned int u = *(const unsigned int*)(base + (size_t)j * 16);
        s0 += bf2f((unsigned short)(u & 0xffff));
        s1 += bf2f((unsigned short)(u >> 16));
    }
    float inv = 1.f / fmaxf((float)deg, 1.0f);
    float m0 = s0 * inv, m1 = s1 * inv;
    float r0 = 0.f, r1 = 0.f;
#pragma unroll 7
    for (int i = 0; i < 35; ++i) {
        float xvi = xn[g_][i];
        r0 = fmaf(xvi, root3[i * 160 + o], r0);
        r1 = fmaf(xvi, root3[i * 160 + o + 1], r1);
    }
    float h0 = m0 + r0 + bias3[o];
    float h1 = m1 + r1 + bias3[o + 1];
    float z0 = (h0 - rm[o]) * (g[o] * rsqrtf(rv[o] + EPSB)) + be[o];
    float z1 = (h1 - rm[o + 1]) * (g[o + 1] * rsqrtf(rv[o + 1] + EPSB)) + be[o + 1];
    float2 res = make_float2(1.f / (1.f + expf(-z0)), 1.f / (1.f + expf(-z1)));
    *(float2*)(x3 + n * 160 + o) = res;
}

// ----------------------------------------------------------- gram ----------

__global__ void k_gram(const float* __restrict__ x3, float* __restrict__ part) {
    int tx = threadIdx.x, ty = threadIdx.y;
    int i = blockIdx.x * 64 + tx * 4;
    int j = blockIdx.y * 64 + ty * 4;
    if (i >= 160 || j >= 160) return;
    int k0 = blockIdx.z * 50;
    float acc[4][4];
#pragma unroll
    for (int r = 0; r < 4; ++r)
#pragma unroll
        for (int c = 0; c < 4; ++c) acc[r][c] = 0.f;
#pragma unroll 5
    for (int k = k0; k < k0 + 50; ++k) {
        float4 av = *(const float4*)&x3[k * 160 + i];
        float4 bv = *(const float4*)&x3[k * 160 + j];
        float ar[4] = {av.x, av.y, av.z, av.w};
        float br[4] = {bv.x, bv.y, bv.z, bv.w};
#pragma unroll
        for (int r = 0; r < 4; ++r)
#pragma unroll
            for (int c = 0; c < 4; ++c) acc[r][c] = fmaf(ar[r], br[c], acc[r][c]);
    }
    float* pp = part + (size_t)blockIdx.z * 25600;
#pragma unroll
    for (int r = 0; r < 4; ++r)
#pragma unroll
        for (int c = 0; c < 4; ++c) pp[(i + r) * 160 + (j + c)] = acc[r][c];
}

__global__ void k_reduce(const float* __restrict__ part, float* __restrict__ out) {
    int t = blockIdx.x * 256 + threadIdx.x;
    if (t >= 25600) return;
    float s = 0.f;
#pragma unroll 10
    for (int z = 0; z < GZ; ++z) s += part[(size_t)z * 25600 + t];
    out[t] = s;
}

// ----------------------------------------------------------------- launch --

extern "C" void kernel_launch(void* const* d_in, const int* in_sizes, int n_in,
                              void* d_out, int out_size, void* d_ws, size_t ws_size,
                              hipStream_t stream) {
    const float* x     = (const float*)d_in[0];
    const int*   ei    = (const int*)d_in[1];
    const float* ea    = (const float*)d_in[2];
    const float* W1    = (const float*)d_in[3];
    const float* b1    = (const float*)d_in[4];
    const float* root1 = (const float*)d_in[5];
    const float* bias1 = (const float*)d_in[6];
    const float* g1    = (const float*)d_in[7];
    const float* be1   = (const float*)d_in[8];
    const float* rm1   = (const float*)d_in[9];
    const float* rv1   = (const float*)d_in[10];
    const float* W3    = (const float*)d_in[11];
    const float* b3    = (const float*)d_in[12];
    const float* root3 = (const float*)d_in[13];
    const float* bias3 = (const float*)d_in[14];
    const float* g3    = (const float*)d_in[15];
    const float* be3   = (const float*)d_in[16];
    const float* rm3   = (const float*)d_in[17];
    const float* rv3   = (const float*)d_in[18];
    float* out = (float*)d_out;

    // ---- workspace layout (byte offsets, all 16B-aligned) ----
    char* wsb = (char*)d_ws;
    int*   counts = (int*)(wsb + 0);                    //  20480 B
    int*   cursor = (int*)(wsb + 20480);                //  20480 B
    int*   offs   = (int*)(wsb + 40960);                //  20480 B
    int*   eslot  = (int*)(wsb + 61440);                // 320512 B -> end 381952
    float* x_p    = (float*)(wsb + 381952);             // 720000 B -> end 1101952
    float* x1p    = (float*)(wsb + 1101952);            // 720000 B -> end 1821952
    float* x3     = (float*)(wsb + 1821952);            // 3.2 MB  -> end 5021952
    unsigned short* msg1 = (unsigned short*)(wsb + 5021952);  // 5.76 MB -> end 10781952
    unsigned short* msg3 = (unsigned short*)(wsb + 10781952); // 25.6 MB -> end 36381952
    float* part   = (float*)(wsb + 5021952);            // 10.24 MB, aliases msg1 (dead)

    hipMemsetAsync(d_ws, 0, (size_t)2 * 5120 * sizeof(int), stream);  // counts+cursor

    int eb = (NE + 255) / 256;
    k_prep <<<(NN * 36 + 255) / 256, 256, 0, stream>>>(x, x_p, ei, counts);
    k_scan <<<1, 256, 0, stream>>>(counts, offs);
    k_edge1<<<eb, 256, 0, stream>>>(ei, ea, offs, cursor, eslot, x_p, W1, b1, msg1);
    k_sum1 <<<(NN * 36 + 255) / 256, 256, 0, stream>>>(offs, msg1, x_p,
                                                       root1, bias1, g1, be1, rm1, rv1, x1p);
    k_edge3<<<dim3(eb, 10), 256, 0, stream>>>(ei, ea, eslot, x1p, W3, b3, msg3);
    k_sum3 <<<1250, 320, 0, stream>>>(offs, msg3, x1p,
                                      root3, bias3, g3, be3, rm3, rv3, x3);
    k_gram <<<dim3(3, 3, GZ), dim3(16, 16), 0, stream>>>(x3, part);
    k_reduce<<<(25600 + 255) / 256, 256, 0, stream>>>(part, out);
}